// Round 6
// baseline (391.514 us; speedup 1.0000x reference)
//
#include <hip/hip_runtime.h>
#include <math.h>

#define NB 8192
#define T 65
#define Q 20
#define D 100
#define D4 25        // D/4
#define SP 24        // sS row pitch in floats (6 float4, 16B-aligned rows)
#define SP4 6

__global__ __launch_bounds__(256) void attn_fused_kernel(
    const float* __restrict__ Hg,   // [B,T,D]
    const float* __restrict__ Ug,   // [B,Q,D]
    const float* __restrict__ Ws1,  // [T,D] (tiled single row)
    const float* __restrict__ Ws2,  // [Q,D]
    const float* __restrict__ Ws3,  // [T,D]
    float* __restrict__ Gg)         // [B,T,4D]
{
    __shared__ float4 sH4[T*D4];        // 26000 B
    __shared__ float4 sU4[Q*D4];        //  8000 B
    __shared__ float4 sU3e4[(Q+1)*D4];  //  8400 B: rows 0..19 = U*w3, row 20 = w1
    __shared__ float4 sS4[T*SP4];       //  6240 B (scores -> at in place)
    __shared__ float4 sHtilP[4][D4];    //  1600 B (per-wave Htil partials)
    __shared__ float4 sU1q4[5];         //    80 B
    __shared__ float  sH1[T];
    __shared__ float  sBeta[T];
    __shared__ float  sBsm[T];

    const int b   = blockIdx.x;
    const int tid = threadIdx.x;
    const float4* Hb = (const float4*)(Hg + (size_t)b * (T*D));
    const float4* Ub = (const float4*)(Ug + (size_t)b * (Q*D));
    float* sSf = (float*)sS4;

    // ---- P1: stage H, U, U*w3 (from in-flight regs), w1 row ----
    for (int i = tid; i < T*D4; i += 256) sH4[i] = Hb[i];
    {
        const float4* w3g = (const float4*)Ws3;   // row 0 (all rows identical)
        for (int i = tid; i < Q*D4; i += 256) {
            const float4 u = Ub[i];
            sU4[i] = u;
            const int dd = i - (i/D4)*D4;
            const float4 w = w3g[dd];
            float4 v; v.x=u.x*w.x; v.y=u.y*w.y; v.z=u.z*w.z; v.w=u.w*w.w;
            sU3e4[i] = v;
        }
        if (tid < D4) sU3e4[Q*D4 + tid] = ((const float4*)Ws1)[tid];
    }
    __syncthreads();

    // ---- P3: S''[t,c] = H[t]·U3e[c] (65x21 GEMM; 4t x 3c, 119 lanes, waves 0-1)
    //      H operand read from GLOBAL (L2-warm; offloads the LDS unit)
    //      wave 2 lanes 128..147 concurrently: U1[q] = U[q]·w2 ----
    if (tid < 119) {
        const int tg = tid / 7;          // 0..16
        const int jg = tid - tg*7;       // 0..6
        int rb0 = ((tg*4 + 0) < T ? (tg*4 + 0) : T-1) * D4;
        int rb1 = ((tg*4 + 1) < T ? (tg*4 + 1) : T-1) * D4;
        int rb2 = ((tg*4 + 2) < T ? (tg*4 + 2) : T-1) * D4;
        int rb3 = ((tg*4 + 3) < T ? (tg*4 + 3) : T-1) * D4;
        float acc[4][3];
        #pragma unroll
        for (int i = 0; i < 4; ++i)
            #pragma unroll
            for (int k = 0; k < 3; ++k) acc[i][k] = 0.f;
        #pragma unroll 5
        for (int d4 = 0; d4 < D4; ++d4) {
            float4 h0 = Hb[rb0 + d4];
            float4 h1 = Hb[rb1 + d4];
            float4 h2 = Hb[rb2 + d4];
            float4 h3 = Hb[rb3 + d4];
            #pragma unroll
            for (int k = 0; k < 3; ++k) {
                const float4 w = sU3e4[(jg*3+k)*D4 + d4];
                acc[0][k] = fmaf(h0.x, w.x, acc[0][k]); acc[0][k] = fmaf(h0.y, w.y, acc[0][k]);
                acc[0][k] = fmaf(h0.z, w.z, acc[0][k]); acc[0][k] = fmaf(h0.w, w.w, acc[0][k]);
                acc[1][k] = fmaf(h1.x, w.x, acc[1][k]); acc[1][k] = fmaf(h1.y, w.y, acc[1][k]);
                acc[1][k] = fmaf(h1.z, w.z, acc[1][k]); acc[1][k] = fmaf(h1.w, w.w, acc[1][k]);
                acc[2][k] = fmaf(h2.x, w.x, acc[2][k]); acc[2][k] = fmaf(h2.y, w.y, acc[2][k]);
                acc[2][k] = fmaf(h2.z, w.z, acc[2][k]); acc[2][k] = fmaf(h2.w, w.w, acc[2][k]);
                acc[3][k] = fmaf(h3.x, w.x, acc[3][k]); acc[3][k] = fmaf(h3.y, w.y, acc[3][k]);
                acc[3][k] = fmaf(h3.z, w.z, acc[3][k]); acc[3][k] = fmaf(h3.w, w.w, acc[3][k]);
            }
        }
        #pragma unroll
        for (int i = 0; i < 4; ++i) {
            const int t = tg*4 + i;
            if (t < T) {
                #pragma unroll
                for (int k = 0; k < 3; ++k) {
                    const int cc = jg*3 + k;
                    if (cc < Q) sSf[t*SP + cc] = acc[i][k];
                    else        sH1[t] = acc[i][k];       // cc == 20: h1[t]
                }
            }
        }
    } else if (tid >= 128 && tid < 128 + Q) {
        const int q = tid - 128;
        const float4* ur = sU4 + q*D4;
        const float4* w2 = (const float4*)Ws2;
        float acc = 0.f;
        #pragma unroll
        for (int k = 0; k < D4; ++k) {
            const float4 u = ur[k], w = w2[k];
            acc = fmaf(u.x, w.x, acc); acc = fmaf(u.y, w.y, acc);
            acc = fmaf(u.z, w.z, acc); acc = fmaf(u.w, w.w, acc);
        }
        ((float*)sU1q4)[q] = acc;
    }
    __syncthreads();

    // ---- P4: add U1, softmax over q (in place), beta[t] = h1[t] + max ----
    if (tid < T) {
        const int t = tid;
        float4 r[5];
        #pragma unroll
        for (int c = 0; c < 5; ++c) {
            r[c] = sS4[t*SP4 + c];
            const float4 u1 = sU1q4[c];
            r[c].x += u1.x; r[c].y += u1.y; r[c].z += u1.z; r[c].w += u1.w;
        }
        float m = -1e30f;
        #pragma unroll
        for (int c = 0; c < 5; ++c)
            m = fmaxf(m, fmaxf(fmaxf(r[c].x, r[c].y), fmaxf(r[c].z, r[c].w)));
        float s = 0.f;
        #pragma unroll
        for (int c = 0; c < 5; ++c) {
            r[c].x = __expf(r[c].x - m); r[c].y = __expf(r[c].y - m);
            r[c].z = __expf(r[c].z - m); r[c].w = __expf(r[c].w - m);
            s += r[c].x + r[c].y + r[c].z + r[c].w;
        }
        const float inv = 1.f / s;
        #pragma unroll
        for (int c = 0; c < 5; ++c) {
            r[c].x *= inv; r[c].y *= inv; r[c].z *= inv; r[c].w *= inv;
            sS4[t*SP4 + c] = r[c];
        }
        sBeta[t] = sH1[t] + m;
    }
    __syncthreads();

    // ---- P5: softmax over t of beta (wave 0; lane 0 also owns t=64) ----
    if (tid < 64) {
        const float v0 = sBeta[tid];
        const float v1 = (tid == 0) ? sBeta[64] : -1e30f;
        float mx = fmaxf(v0, v1);
        #pragma unroll
        for (int off = 32; off >= 1; off >>= 1)
            mx = fmaxf(mx, __shfl_xor(mx, off, 64));
        const float e0 = __expf(v0 - mx);
        const float e1 = (tid == 0) ? __expf(v1 - mx) : 0.f;
        float s = e0 + e1;
        #pragma unroll
        for (int off = 32; off >= 1; off >>= 1)
            s += __shfl_xor(s, off, 64);
        const float inv = 1.f / s;
        sBsm[tid] = e0 * inv;
        if (tid == 0) sBsm[64] = e1 * inv;
    }
    __syncthreads();

    // ---- P6: Htil partials, one per wave; H from GLOBAL (L2-warm) ----
    {
        const int wv = tid >> 6, lane = tid & 63;
        if (lane < D4) {
            float4 acc = {0.f, 0.f, 0.f, 0.f};
            for (int t = wv; t < T; t += 4) {
                const float bt = sBsm[t];
                const float4 h = Hb[t*D4 + lane];
                acc.x = fmaf(bt, h.x, acc.x); acc.y = fmaf(bt, h.y, acc.y);
                acc.z = fmaf(bt, h.z, acc.z); acc.w = fmaf(bt, h.w, acc.w);
            }
            sHtilP[wv][lane] = acc;
        }
    }
    __syncthreads();

    // ---- P7: output. 2t x 25g lanes per pair; U hoisted to registers ----
    {
        const int wv   = tid >> 6;
        const int lane = tid & 63;
        const int tsel = (lane < 50) ? (lane / 25) : 0;
        const int g    = (lane < 50) ? (lane - tsel*25) : (lane - 50);
        const bool act = (lane < 50);
        float* Gb = Gg + (size_t)b * (T*4*D);

        const float4 p0 = sHtilP[0][g], p1 = sHtilP[1][g], p2 = sHtilP[2][g], p3 = sHtilP[3][g];
        float4 htil;
        htil.x = p0.x+p1.x+p2.x+p3.x; htil.y = p0.y+p1.y+p2.y+p3.y;
        htil.z = p0.z+p1.z+p2.z+p3.z; htil.w = p0.w+p1.w+p2.w+p3.w;

        float4 u[Q];                       // 80 VGPRs, static-indexed
        #pragma unroll
        for (int q = 0; q < Q; ++q) u[q] = sU4[q*D4 + g];

        for (int pr = wv; pr < 33; pr += 4) {
            const int t   = pr*2 + tsel;
            const bool val = act && (t < T);
            const int tr  = val ? t : 0;

            const float4 a0 = sS4[tr*SP4 + 0];
            const float4 a1 = sS4[tr*SP4 + 1];
            const float4 a2 = sS4[tr*SP4 + 2];
            const float4 a3 = sS4[tr*SP4 + 3];
            const float4 a4 = sS4[tr*SP4 + 4];

            float4 acc = {0.f, 0.f, 0.f, 0.f};
            #define QSTEP(av, comp, qq) { \
                acc.x = fmaf(av.comp, u[qq].x, acc.x); \
                acc.y = fmaf(av.comp, u[qq].y, acc.y); \
                acc.z = fmaf(av.comp, u[qq].z, acc.z); \
                acc.w = fmaf(av.comp, u[qq].w, acc.w); }
            QSTEP(a0,x,0)  QSTEP(a0,y,1)  QSTEP(a0,z,2)  QSTEP(a0,w,3)
            QSTEP(a1,x,4)  QSTEP(a1,y,5)  QSTEP(a1,z,6)  QSTEP(a1,w,7)
            QSTEP(a2,x,8)  QSTEP(a2,y,9)  QSTEP(a2,z,10) QSTEP(a2,w,11)
            QSTEP(a3,x,12) QSTEP(a3,y,13) QSTEP(a3,z,14) QSTEP(a3,w,15)
            QSTEP(a4,x,16) QSTEP(a4,y,17) QSTEP(a4,z,18) QSTEP(a4,w,19)
            #undef QSTEP

            const float4 hv = sH4[tr*D4 + g];
            if (val) {
                float4 hu, hh;
                hu.x = hv.x*acc.x;  hu.y = hv.y*acc.y;  hu.z = hv.z*acc.z;  hu.w = hv.w*acc.w;
                hh.x = hv.x*htil.x; hh.y = hv.y*htil.y; hh.z = hv.z*htil.z; hh.w = hv.w*htil.w;
                float4* base = (float4*)(Gb + (size_t)t*(4*D));
                base[g]        = hv;
                base[D4 + g]   = acc;
                base[2*D4 + g] = hu;
                base[3*D4 + g] = hh;
            }
        }
    }
}

extern "C" void kernel_launch(void* const* d_in, const int* in_sizes, int n_in,
                              void* d_out, int out_size, void* d_ws, size_t ws_size,
                              hipStream_t stream) {
    const float* H   = (const float*)d_in[0];
    const float* U   = (const float*)d_in[1];
    const float* Ws1 = (const float*)d_in[2];
    const float* Ws2 = (const float*)d_in[3];
    const float* Ws3 = (const float*)d_in[4];
    float* G = (float*)d_out;
    hipLaunchKernelGGL(attn_fused_kernel, dim3(NB), dim3(256), 0, stream,
                       H, U, Ws1, Ws2, Ws3, G);
}

// Round 7
// 330.194 us; speedup vs baseline: 1.1857x; 1.1857x over previous
//
#include <hip/hip_runtime.h>
#include <math.h>

#define NB 8192
#define T 65
#define Q 20
#define D 100
#define D4 25        // D/4
#define SP 24        // sS row pitch in floats (6 float4, 16B-aligned rows)
#define SP4 6

__global__ __launch_bounds__(256) void attn_fused_kernel(
    const float* __restrict__ Hg,   // [B,T,D]
    const float* __restrict__ Ug,   // [B,Q,D]
    const float* __restrict__ Ws1,  // [T,D] (tiled single row)
    const float* __restrict__ Ws2,  // [Q,D]
    const float* __restrict__ Ws3,  // [T,D]
    float* __restrict__ Gg)         // [B,T,4D]
{
    __shared__ float4 sH4[T*D4];        // 26000 B
    __shared__ float4 sU4[Q*D4];        //  8000 B
    __shared__ float4 sU3e4[(Q+1)*D4];  //  8400 B: rows 0..19 = U*w3, row 20 = w1
    __shared__ float4 sS4[T*SP4];       //  6240 B (scores -> at in place)
    __shared__ float4 sHtilP[2][D4];    //   800 B (waves 0-1 partials)
    __shared__ float4 sU1q4[5];         //    80 B
    __shared__ float  sH1[T];
    __shared__ float  sBeta[T];
    __shared__ float  sBsm[T];

    const int b   = blockIdx.x;
    const int tid = threadIdx.x;
    const int wv  = tid >> 6;
    const int lane = tid & 63;
    const float4* Hb = (const float4*)(Hg + (size_t)b * (T*D));
    const float4* Ub = (const float4*)(Ug + (size_t)b * (Q*D));
    float* Gb = Gg + (size_t)b * (T*4*D);
    float* sSf = (float*)sS4;

    // ---- P1: stage H, U, U*w3 (from in-flight regs), w1 row ----
    for (int i = tid; i < T*D4; i += 256) sH4[i] = Hb[i];
    {
        const float4* w3g = (const float4*)Ws3;   // row 0 (all rows identical)
        for (int i = tid; i < Q*D4; i += 256) {
            const float4 u = Ub[i];
            sU4[i] = u;
            const int dd = i - (i/D4)*D4;
            const float4 w = w3g[dd];
            float4 v; v.x=u.x*w.x; v.y=u.y*w.y; v.z=u.z*w.z; v.w=u.w*w.w;
            sU3e4[i] = v;
        }
        if (tid < D4) sU3e4[Q*D4 + tid] = ((const float4*)Ws1)[tid];
    }
    __syncthreads();   // bar1

    // ---- Window A (waves 0-1): P3 S''[t,c] = H[t]·U3e[c], 4t x 3c, 119 lanes.
    //      Window A (waves 2-3): U1 (wave-2 lanes) then stream G segment 1 = H.
    if (tid < 119) {
        const int tg = tid / 7;          // 0..16
        const int jg = tid - tg*7;       // 0..6
        int rb0 = ((tg*4 + 0) < T ? (tg*4 + 0) : T-1) * D4;
        int rb1 = ((tg*4 + 1) < T ? (tg*4 + 1) : T-1) * D4;
        int rb2 = ((tg*4 + 2) < T ? (tg*4 + 2) : T-1) * D4;
        int rb3 = ((tg*4 + 3) < T ? (tg*4 + 3) : T-1) * D4;
        float acc[4][3];
        #pragma unroll
        for (int i = 0; i < 4; ++i)
            #pragma unroll
            for (int k = 0; k < 3; ++k) acc[i][k] = 0.f;
        #pragma unroll 5
        for (int d4 = 0; d4 < D4; ++d4) {
            float4 h0 = sH4[rb0 + d4];
            float4 h1 = sH4[rb1 + d4];
            float4 h2 = sH4[rb2 + d4];
            float4 h3 = sH4[rb3 + d4];
            #pragma unroll
            for (int k = 0; k < 3; ++k) {
                const float4 w = sU3e4[(jg*3+k)*D4 + d4];
                acc[0][k] = fmaf(h0.x, w.x, acc[0][k]); acc[0][k] = fmaf(h0.y, w.y, acc[0][k]);
                acc[0][k] = fmaf(h0.z, w.z, acc[0][k]); acc[0][k] = fmaf(h0.w, w.w, acc[0][k]);
                acc[1][k] = fmaf(h1.x, w.x, acc[1][k]); acc[1][k] = fmaf(h1.y, w.y, acc[1][k]);
                acc[1][k] = fmaf(h1.z, w.z, acc[1][k]); acc[1][k] = fmaf(h1.w, w.w, acc[1][k]);
                acc[2][k] = fmaf(h2.x, w.x, acc[2][k]); acc[2][k] = fmaf(h2.y, w.y, acc[2][k]);
                acc[2][k] = fmaf(h2.z, w.z, acc[2][k]); acc[2][k] = fmaf(h2.w, w.w, acc[2][k]);
                acc[3][k] = fmaf(h3.x, w.x, acc[3][k]); acc[3][k] = fmaf(h3.y, w.y, acc[3][k]);
                acc[3][k] = fmaf(h3.z, w.z, acc[3][k]); acc[3][k] = fmaf(h3.w, w.w, acc[3][k]);
            }
        }
        #pragma unroll
        for (int i = 0; i < 4; ++i) {
            const int t = tg*4 + i;
            if (t < T) {
                #pragma unroll
                for (int k = 0; k < 3; ++k) {
                    const int cc = jg*3 + k;
                    if (cc < Q) sSf[t*SP + cc] = acc[i][k];
                    else        sH1[t] = acc[i][k];       // cc == 20: h1[t]
                }
            }
        }
    } else if (tid >= 128) {
        if (tid < 128 + Q) {   // wave 2 head: U1[q] = U[q]·w2 (LDS, 25 instrs)
            const int q = tid - 128;
            const float4* ur = sU4 + q*D4;
            const float4* w2 = (const float4*)Ws2;
            float acc = 0.f;
            #pragma unroll
            for (int k = 0; k < D4; ++k) {
                const float4 u = ur[k], w = w2[k];
                acc = fmaf(u.x, w.x, acc); acc = fmaf(u.y, w.y, acc);
                acc = fmaf(u.z, w.z, acc); acc = fmaf(u.w, w.w, acc);
            }
            ((float*)sU1q4)[q] = acc;
        }
        // waves 2-3: stream segment 1 (G[:, :, 0:D] = H) from global (L2-warm)
        for (int i = tid - 128; i < T*D4; i += 128) {
            const int t = i / D4;
            const int g = i - t*D4;
            const float4 hv = Hb[i];
            ((float4*)(Gb + (size_t)t*(4*D)))[g] = hv;
        }
    }
    __syncthreads();   // bar2

    // ---- P4: add U1, softmax over q (in place), beta[t] = h1[t] + max ----
    if (tid < T) {
        const int t = tid;
        float4 r[5];
        #pragma unroll
        for (int c = 0; c < 5; ++c) {
            r[c] = sS4[t*SP4 + c];
            const float4 u1 = sU1q4[c];
            r[c].x += u1.x; r[c].y += u1.y; r[c].z += u1.z; r[c].w += u1.w;
        }
        float m = -1e30f;
        #pragma unroll
        for (int c = 0; c < 5; ++c)
            m = fmaxf(m, fmaxf(fmaxf(r[c].x, r[c].y), fmaxf(r[c].z, r[c].w)));
        float s = 0.f;
        #pragma unroll
        for (int c = 0; c < 5; ++c) {
            r[c].x = __expf(r[c].x - m); r[c].y = __expf(r[c].y - m);
            r[c].z = __expf(r[c].z - m); r[c].w = __expf(r[c].w - m);
            s += r[c].x + r[c].y + r[c].z + r[c].w;
        }
        const float inv = 1.f / s;
        #pragma unroll
        for (int c = 0; c < 5; ++c) {
            r[c].x *= inv; r[c].y *= inv; r[c].z *= inv; r[c].w *= inv;
            sS4[t*SP4 + c] = r[c];
        }
        sBeta[t] = sH1[t] + m;
    }
    __syncthreads();   // bar3

    // ---- P5: softmax over t of beta (wave 0; lane 0 also owns t=64) ----
    if (tid < 64) {
        const float v0 = sBeta[tid];
        const float v1 = (tid == 0) ? sBeta[64] : -1e30f;
        float mx = fmaxf(v0, v1);
        #pragma unroll
        for (int off = 32; off >= 1; off >>= 1)
            mx = fmaxf(mx, __shfl_xor(mx, off, 64));
        const float e0 = __expf(v0 - mx);
        const float e1 = (tid == 0) ? __expf(v1 - mx) : 0.f;
        float s = e0 + e1;
        #pragma unroll
        for (int off = 32; off >= 1; off >>= 1)
            s += __shfl_xor(s, off, 64);
        const float inv = 1.f / s;
        sBsm[tid] = e0 * inv;
        if (tid == 0) sBsm[64] = e1 * inv;
    }
    __syncthreads();   // bar4

    // ---- P6: Htil partials on waves 0-1 (even/odd t), from sH4 ----
    if (wv < 2 && lane < D4) {
        float4 acc = {0.f, 0.f, 0.f, 0.f};
        for (int t = wv; t < T; t += 2) {
            const float bt = sBsm[t];
            const float4 h = sH4[t*D4 + lane];
            acc.x = fmaf(bt, h.x, acc.x); acc.y = fmaf(bt, h.y, acc.y);
            acc.z = fmaf(bt, h.z, acc.z); acc.w = fmaf(bt, h.w, acc.w);
        }
        sHtilP[wv][lane] = acc;
    }
    __syncthreads();   // bar5

    // ---- P7': segments 2,3,4. 2t x 25g lanes per pair; U hoisted to registers ----
    {
        const int tsel = (lane < 50) ? (lane / 25) : 0;
        const int g    = (lane < 50) ? (lane - tsel*25) : (lane - 50);
        const bool act = (lane < 50);

        const float4 p0 = sHtilP[0][g], p1 = sHtilP[1][g];
        float4 htil;
        htil.x = p0.x+p1.x; htil.y = p0.y+p1.y;
        htil.z = p0.z+p1.z; htil.w = p0.w+p1.w;

        float4 u[Q];                       // 80 VGPRs, static-indexed
        #pragma unroll
        for (int q = 0; q < Q; ++q) u[q] = sU4[q*D4 + g];

        for (int pr = wv; pr < 33; pr += 4) {
            const int t   = pr*2 + tsel;
            const bool val = act && (t < T);
            const int tr  = val ? t : 0;

            const float4 a0 = sS4[tr*SP4 + 0];
            const float4 a1 = sS4[tr*SP4 + 1];
            const float4 a2 = sS4[tr*SP4 + 2];
            const float4 a3 = sS4[tr*SP4 + 3];
            const float4 a4 = sS4[tr*SP4 + 4];

            float4 acc = {0.f, 0.f, 0.f, 0.f};
            #define QSTEP(av, comp, qq) { \
                acc.x = fmaf(av.comp, u[qq].x, acc.x); \
                acc.y = fmaf(av.comp, u[qq].y, acc.y); \
                acc.z = fmaf(av.comp, u[qq].z, acc.z); \
                acc.w = fmaf(av.comp, u[qq].w, acc.w); }
            QSTEP(a0,x,0)  QSTEP(a0,y,1)  QSTEP(a0,z,2)  QSTEP(a0,w,3)
            QSTEP(a1,x,4)  QSTEP(a1,y,5)  QSTEP(a1,z,6)  QSTEP(a1,w,7)
            QSTEP(a2,x,8)  QSTEP(a2,y,9)  QSTEP(a2,z,10) QSTEP(a2,w,11)
            QSTEP(a3,x,12) QSTEP(a3,y,13) QSTEP(a3,z,14) QSTEP(a3,w,15)
            QSTEP(a4,x,16) QSTEP(a4,y,17) QSTEP(a4,z,18) QSTEP(a4,w,19)
            #undef QSTEP

            const float4 hv = sH4[tr*D4 + g];
            if (val) {
                float4 hu, hh;
                hu.x = hv.x*acc.x;  hu.y = hv.y*acc.y;  hu.z = hv.z*acc.z;  hu.w = hv.w*acc.w;
                hh.x = hv.x*htil.x; hh.y = hv.y*htil.y; hh.z = hv.z*htil.z; hh.w = hv.w*htil.w;
                float4* base = (float4*)(Gb + (size_t)t*(4*D));
                base[D4 + g]   = acc;
                base[2*D4 + g] = hu;
                base[3*D4 + g] = hh;
            }
        }
    }
}

extern "C" void kernel_launch(void* const* d_in, const int* in_sizes, int n_in,
                              void* d_out, int out_size, void* d_ws, size_t ws_size,
                              hipStream_t stream) {
    const float* H   = (const float*)d_in[0];
    const float* U   = (const float*)d_in[1];
    const float* Ws1 = (const float*)d_in[2];
    const float* Ws2 = (const float*)d_in[3];
    const float* Ws3 = (const float*)d_in[4];
    float* G = (float*)d_out;
    hipLaunchKernelGGL(attn_fused_kernel, dim3(NB), dim3(256), 0, stream,
                       H, U, Ws1, Ws2, Ws3, G);
}

// Round 8
// 267.879 us; speedup vs baseline: 1.4615x; 1.2326x over previous
//
#include <hip/hip_runtime.h>
#include <math.h>

#define NB 8192
#define T 65
#define Q 20
#define D 100
#define D4 25        // D/4
#define SP4 5        // sS row pitch in float4 (= Q floats exactly)

__global__ __launch_bounds__(256, 4) void attn_fused_kernel(
    const float* __restrict__ Hg,   // [B,T,D]
    const float* __restrict__ Ug,   // [B,Q,D]
    const float* __restrict__ Ws1,  // [T,D] (tiled single row)
    const float* __restrict__ Ws2,  // [Q,D]
    const float* __restrict__ Ws3,  // [T,D]
    float* __restrict__ Gg)         // [B,T,4D]
{
    // 26000 + 8400 + 5200 + 800 + 80 + 260 = 40740 B -> 4 blocks/CU (160 KiB)
    __shared__ float4 sH4[T*D4];          // 26000 B
    __shared__ float4 sU3e4[(Q+1)*D4];    //  8400 B: rows 0..19 = U*w3, row 20 = w1
    __shared__ float4 sS4[T*SP4];         //  5200 B (scores -> at in place)
    __shared__ float4 sHtilP[2][D4];      //   800 B (waves 0-1 partials)
    __shared__ float4 sU1q4[5];           //    80 B
    __shared__ float  sScal[T];           //   260 B: h1 -> beta -> bsm (in place)

    const int b    = blockIdx.x;
    const int tid  = threadIdx.x;
    const int wv   = tid >> 6;
    const int lane = tid & 63;
    const float4* Hb = (const float4*)(Hg + (size_t)b * (T*D));
    const float4* Ub = (const float4*)(Ug + (size_t)b * (Q*D));
    float* Gb = Gg + (size_t)b * (T*4*D);
    float* sSf = (float*)sS4;

    // ---- P1: stage H; build U*w3 from in-flight regs; w1 row ----
    for (int i = tid; i < T*D4; i += 256) sH4[i] = Hb[i];
    {
        const float4* w3g = (const float4*)Ws3;   // row 0 (all rows identical)
        for (int i = tid; i < Q*D4; i += 256) {
            const float4 u = Ub[i];
            const int dd = i - (i/D4)*D4;
            const float4 w = w3g[dd];
            float4 v; v.x=u.x*w.x; v.y=u.y*w.y; v.z=u.z*w.z; v.w=u.w*w.w;
            sU3e4[i] = v;
        }
        if (tid < D4) sU3e4[Q*D4 + tid] = ((const float4*)Ws1)[tid];
    }
    __syncthreads();   // bar1

    // ---- P3: S''[t,c] = H[t]·U3e[c] (65x21 GEMM; 4t x 3c, 119 lanes, waves 0-1)
    //      wave 2 (tid 128..147) concurrently: U1[q] = U[q]·w2 from GLOBAL (L2-warm)
    if (tid < 119) {
        const int tg = tid / 7;          // 0..16
        const int jg = tid - tg*7;       // 0..6
        int rb0 = ((tg*4 + 0) < T ? (tg*4 + 0) : T-1) * D4;
        int rb1 = ((tg*4 + 1) < T ? (tg*4 + 1) : T-1) * D4;
        int rb2 = ((tg*4 + 2) < T ? (tg*4 + 2) : T-1) * D4;
        int rb3 = ((tg*4 + 3) < T ? (tg*4 + 3) : T-1) * D4;
        float acc[4][3];
        #pragma unroll
        for (int i = 0; i < 4; ++i)
            #pragma unroll
            for (int k = 0; k < 3; ++k) acc[i][k] = 0.f;
        #pragma unroll 5
        for (int d4 = 0; d4 < D4; ++d4) {
            float4 h0 = sH4[rb0 + d4];
            float4 h1 = sH4[rb1 + d4];
            float4 h2 = sH4[rb2 + d4];
            float4 h3 = sH4[rb3 + d4];
            #pragma unroll
            for (int k = 0; k < 3; ++k) {
                const float4 w = sU3e4[(jg*3+k)*D4 + d4];
                acc[0][k] = fmaf(h0.x, w.x, acc[0][k]); acc[0][k] = fmaf(h0.y, w.y, acc[0][k]);
                acc[0][k] = fmaf(h0.z, w.z, acc[0][k]); acc[0][k] = fmaf(h0.w, w.w, acc[0][k]);
                acc[1][k] = fmaf(h1.x, w.x, acc[1][k]); acc[1][k] = fmaf(h1.y, w.y, acc[1][k]);
                acc[1][k] = fmaf(h1.z, w.z, acc[1][k]); acc[1][k] = fmaf(h1.w, w.w, acc[1][k]);
                acc[2][k] = fmaf(h2.x, w.x, acc[2][k]); acc[2][k] = fmaf(h2.y, w.y, acc[2][k]);
                acc[2][k] = fmaf(h2.z, w.z, acc[2][k]); acc[2][k] = fmaf(h2.w, w.w, acc[2][k]);
                acc[3][k] = fmaf(h3.x, w.x, acc[3][k]); acc[3][k] = fmaf(h3.y, w.y, acc[3][k]);
                acc[3][k] = fmaf(h3.z, w.z, acc[3][k]); acc[3][k] = fmaf(h3.w, w.w, acc[3][k]);
            }
        }
        #pragma unroll
        for (int i = 0; i < 4; ++i) {
            const int t = tg*4 + i;
            if (t < T) {
                #pragma unroll
                for (int k = 0; k < 3; ++k) {
                    const int cc = jg*3 + k;
                    if (cc < Q) sSf[t*Q + cc] = acc[i][k];
                    else        sScal[t] = acc[i][k];     // cc == 20: h1[t]
                }
            }
        }
    } else if (tid >= 128 && tid < 128 + Q) {
        const int q = tid - 128;
        const float4* ur = Ub + q*D4;                     // global, L2-warm
        const float4* w2 = (const float4*)Ws2;
        float acc = 0.f;
        #pragma unroll 5
        for (int k = 0; k < D4; ++k) {
            const float4 u = ur[k], w = w2[k];
            acc = fmaf(u.x, w.x, acc); acc = fmaf(u.y, w.y, acc);
            acc = fmaf(u.z, w.z, acc); acc = fmaf(u.w, w.w, acc);
        }
        ((float*)sU1q4)[q] = acc;
    }
    __syncthreads();   // bar2

    // ---- P4: add U1, softmax over q (in place), beta[t] = h1[t] + max ----
    if (tid < T) {
        const int t = tid;
        float4 r[SP4];
        #pragma unroll
        for (int c = 0; c < SP4; ++c) {
            r[c] = sS4[t*SP4 + c];
            const float4 u1 = sU1q4[c];
            r[c].x += u1.x; r[c].y += u1.y; r[c].z += u1.z; r[c].w += u1.w;
        }
        float m = -1e30f;
        #pragma unroll
        for (int c = 0; c < SP4; ++c)
            m = fmaxf(m, fmaxf(fmaxf(r[c].x, r[c].y), fmaxf(r[c].z, r[c].w)));
        float s = 0.f;
        #pragma unroll
        for (int c = 0; c < SP4; ++c) {
            r[c].x = __expf(r[c].x - m); r[c].y = __expf(r[c].y - m);
            r[c].z = __expf(r[c].z - m); r[c].w = __expf(r[c].w - m);
            s += r[c].x + r[c].y + r[c].z + r[c].w;
        }
        const float inv = 1.f / s;
        #pragma unroll
        for (int c = 0; c < SP4; ++c) {
            r[c].x *= inv; r[c].y *= inv; r[c].z *= inv; r[c].w *= inv;
            sS4[t*SP4 + c] = r[c];
        }
        sScal[t] = sScal[t] + m;     // beta[t] = h1[t] + m (in place)
    }
    __syncthreads();   // bar3

    // ---- P5: softmax over t of beta (wave 0; lane 0 also owns t=64), in place ----
    if (tid < 64) {
        const float v0 = sScal[tid];
        const float v1 = (tid == 0) ? sScal[64] : -1e30f;
        float mx = fmaxf(v0, v1);
        #pragma unroll
        for (int off = 32; off >= 1; off >>= 1)
            mx = fmaxf(mx, __shfl_xor(mx, off, 64));
        const float e0 = __expf(v0 - mx);
        const float e1 = (tid == 0) ? __expf(v1 - mx) : 0.f;
        float s = e0 + e1;
        #pragma unroll
        for (int off = 32; off >= 1; off >>= 1)
            s += __shfl_xor(s, off, 64);
        const float inv = 1.f / s;
        sScal[tid] = e0 * inv;
        if (tid == 0) sScal[64] = e1 * inv;
    }
    __syncthreads();   // bar4

    // ---- P6: Htil partials on waves 0-1 (even/odd t), from sH4 ----
    if (wv < 2 && lane < D4) {
        float4 acc = {0.f, 0.f, 0.f, 0.f};
        for (int t = wv; t < T; t += 2) {
            const float bt = sScal[t];
            const float4 h = sH4[t*D4 + lane];
            acc.x = fmaf(bt, h.x, acc.x); acc.y = fmaf(bt, h.y, acc.y);
            acc.z = fmaf(bt, h.z, acc.z); acc.w = fmaf(bt, h.w, acc.w);
        }
        sHtilP[wv][lane] = acc;
    }
    __syncthreads();   // bar5

    // ---- P7: output. 2t x 25g lanes per pair; U hoisted to regs from GLOBAL;
    //          at-rows loaded STAGGERED (one float4 live at a time) ----
    {
        const int tsel = (lane < 50) ? (lane / 25) : 0;
        const int g    = (lane < 50) ? (lane - tsel*25) : (lane - 50);
        const bool act = (lane < 50);

        const float4 p0 = sHtilP[0][g], p1 = sHtilP[1][g];
        float4 htil;
        htil.x = p0.x+p1.x; htil.y = p0.y+p1.y;
        htil.z = p0.z+p1.z; htil.w = p0.w+p1.w;

        float4 u[Q];                       // 80 VGPRs, static-indexed (global, L2-warm)
        #pragma unroll
        for (int q = 0; q < Q; ++q) u[q] = Ub[q*D4 + g];

        #pragma unroll 1
        for (int pr = wv; pr < 33; pr += 4) {
            const int t   = pr*2 + tsel;
            const bool val = act && (t < T);
            const int tr  = val ? t : 0;

            float4 acc = {0.f, 0.f, 0.f, 0.f};
            #define QSTEP(av, comp, qq) { \
                acc.x = fmaf(av.comp, u[qq].x, acc.x); \
                acc.y = fmaf(av.comp, u[qq].y, acc.y); \
                acc.z = fmaf(av.comp, u[qq].z, acc.z); \
                acc.w = fmaf(av.comp, u[qq].w, acc.w); }
            {
                float4 a = sS4[tr*SP4 + 0];
                QSTEP(a,x,0)  QSTEP(a,y,1)  QSTEP(a,z,2)  QSTEP(a,w,3)
                a = sS4[tr*SP4 + 1];
                QSTEP(a,x,4)  QSTEP(a,y,5)  QSTEP(a,z,6)  QSTEP(a,w,7)
                a = sS4[tr*SP4 + 2];
                QSTEP(a,x,8)  QSTEP(a,y,9)  QSTEP(a,z,10) QSTEP(a,w,11)
                a = sS4[tr*SP4 + 3];
                QSTEP(a,x,12) QSTEP(a,y,13) QSTEP(a,z,14) QSTEP(a,w,15)
                a = sS4[tr*SP4 + 4];
                QSTEP(a,x,16) QSTEP(a,y,17) QSTEP(a,z,18) QSTEP(a,w,19)
            }
            #undef QSTEP

            const float4 hv = sH4[tr*D4 + g];
            if (val) {
                float4 hu, hh;
                hu.x = hv.x*acc.x;  hu.y = hv.y*acc.y;  hu.z = hv.z*acc.z;  hu.w = hv.w*acc.w;
                hh.x = hv.x*htil.x; hh.y = hv.y*htil.y; hh.z = hv.z*htil.z; hh.w = hv.w*htil.w;
                float4* base = (float4*)(Gb + (size_t)t*(4*D));
                base[g]        = hv;
                base[D4 + g]   = acc;
                base[2*D4 + g] = hu;
                base[3*D4 + g] = hh;
            }
        }
    }
}

extern "C" void kernel_launch(void* const* d_in, const int* in_sizes, int n_in,
                              void* d_out, int out_size, void* d_ws, size_t ws_size,
                              hipStream_t stream) {
    const float* H   = (const float*)d_in[0];
    const float* U   = (const float*)d_in[1];
    const float* Ws1 = (const float*)d_in[2];
    const float* Ws2 = (const float*)d_in[3];
    const float* Ws3 = (const float*)d_in[4];
    float* G = (float*)d_out;
    hipLaunchKernelGGL(attn_fused_kernel, dim3(NB), dim3(256), 0, stream,
                       H, U, Ws1, Ws2, Ws3, G);
}